// Round 12
// baseline (1577.978 us; speedup 1.0000x reference)
//
#include <hip/hip_runtime.h>
#include <hip/hip_fp16.h>

constexpr int F_IN  = 9;
constexpr int F_HID = 32;
constexpr int F_OUT = 7;

constexpr int SB_SHIFT = 13;
constexpr int SB_NODES = 1 << SB_SHIFT;          // 8192
constexpr int NSB      = 19;                     // ceil(150000/8192)
constexpr int SB_CAP   = 135424;
constexpr int A_EDGES  = 4096;
constexpr int FB_PER_SB= 32;
constexpr int NBKT     = 586;
constexpr int NBKT_PAD = 608;
constexpr int BCAP     = 4864;
constexpr int B_EDGES  = 4096;
constexpr int B_CHUNKS = (SB_CAP + B_EDGES - 1) / B_EDGES;  // 34
constexpr int GRID     = 896;                    // <= 4 blocks/CU * 256 CU

__device__ __forceinline__ int nt_load_int(const int* p) {
    return __builtin_nontemporal_load(p);
}
__device__ __forceinline__ unsigned pack_h2(float a, float b) {
    return (unsigned)__half_as_ushort(__float2half(a)) |
           ((unsigned)__half_as_ushort(__float2half(b)) << 16);
}
__device__ __forceinline__ float2 unpack_h2(unsigned u) {
    return make_float2(__half2float(__ushort_as_half((unsigned short)(u & 0xffffu))),
                       __half2float(__ushort_as_half((unsigned short)(u >> 16))));
}

// software grid barrier: counters zeroed by k_init each call
__device__ __forceinline__ void gsync(int* bar, int nblk) {
    __syncthreads();
    if (threadIdx.x == 0) {
        __threadfence();                       // release: flush to device scope
        atomicAdd(bar, 1);
        while (__hip_atomic_load(bar, __ATOMIC_ACQUIRE, __HIP_MEMORY_SCOPE_AGENT) < nblk)
            __builtin_amdgcn_s_sleep(4);
    }
    __syncthreads();
    __threadfence();                           // acquire: invalidate stale caches
}

__global__ void k_init(int* __restrict__ bcur, int* __restrict__ bars) {
    int i = blockIdx.x * 256 + threadIdx.x;
    if (i < NBKT_PAD) bcur[i * 16] = i * BCAP;
    if (i < 8) bars[i] = 0;
}

__global__ __launch_bounds__(256, 4) void k_gcn(
    const int* __restrict__ row, const int* __restrict__ col,
    const float* __restrict__ w, const float* __restrict__ x,
    const float* __restrict__ W1, const float* __restrict__ b1,
    const float* __restrict__ W2, const float* __restrict__ b2,
    float* __restrict__ out,
    int* __restrict__ sbA, unsigned short* __restrict__ sbB,
    int* __restrict__ irA, unsigned char* __restrict__ irB,
    int* __restrict__ bcur, int* __restrict__ ghist, int* __restrict__ sbcnt,
    int* __restrict__ bars,
    int4* __restrict__ meta, unsigned* __restrict__ xdh, unsigned* __restrict__ h2dh,
    int N, int E, int nblkA)
{
    __shared__ unsigned char buf[24832];       // staging / weights union
    __shared__ int aux0[256];
    __shared__ int aux1[256];
    __shared__ int aux2[256];
    __shared__ int aux3[256];

    const int tid = threadIdx.x;
    const int G   = gridDim.x;
    const int b0  = blockIdx.x;

    // ---------- P1: per-chunk histogram over superbuckets ----------
    for (int vb = b0; vb < nblkA; vb += G) {
        if (tid < NSB) aux0[tid] = 0;
        __syncthreads();
        int t0 = vb * A_EDGES, kend = min(A_EDGES, E - t0);
        for (int k = tid; k < kend; k += 256)
            atomicAdd(&aux0[col[t0 + k] >> SB_SHIFT], 1);
        __syncthreads();
        if (tid < NSB) ghist[(size_t)tid * nblkA + vb] = aux0[tid];
        __syncthreads();
    }
    gsync(&bars[0], G);

    // ---------- P2: exclusive scan of each superbucket row ----------
    for (int s = b0; s < NSB; s += G) {
        int* r = ghist + (size_t)s * nblkA;
        int per = (nblkA + 255) / 256;
        int i0 = tid * per, i1 = min(i0 + per, nblkA);
        int sum = 0;
        for (int i = i0; i < i1; ++i) sum += r[i];
        aux0[tid] = sum; __syncthreads();
        for (int d = 1; d < 256; d <<= 1) {
            int u = (tid >= d) ? aux0[tid - d] : 0;
            __syncthreads();
            aux0[tid] += u; __syncthreads();
        }
        int run = aux0[tid] - sum;
        for (int i = i0; i < i1; ++i) { int v = r[i]; r[i] = run; run += v; }
        if (tid == 255) sbcnt[s] = run;
        __syncthreads();
    }
    gsync(&bars[1], G);

    // ---------- P3: scatter edges to superbuckets (split planes) ----------
    for (int vb = b0; vb < nblkA; vb += G) {
        if (tid < NSB) {
            aux0[tid] = tid * SB_CAP + ghist[(size_t)tid * nblkA + vb];
            aux1[tid] = 0;
        }
        __syncthreads();
        int t0 = vb * A_EDGES, kend = min(A_EDGES, E - t0);
        for (int k = tid; k < kend; k += 256) {
            int e = t0 + k;
            int c = col[e];
            int s = c >> SB_SHIFT;
            int wq = min((int)(w[e] * 16384.0f + 0.5f), 16383);
            int rw = (row[e] << 14) | wq;
            int rk = atomicAdd(&aux1[s], 1);
            int pos = aux0[s] + rk;
            if (pos < (s + 1) * SB_CAP) {
                sbA[pos] = rw;
                sbB[pos] = (unsigned short)(c & (SB_NODES - 1));
            }
        }
        __syncthreads();
    }
    gsync(&bars[2], G);

    // ---------- P4: superbucket -> 32 final buckets ----------
    {
        int* srw = (int*)buf;                              // 4096 ints
        unsigned short* scl = (unsigned short*)(buf + 16384); // 4096 u16
        for (int vb = b0; vb < NSB * B_CHUNKS; vb += G) {
            int sb = vb / B_CHUNKS, chunk = vb % B_CHUNKS;
            int cnt = min(sbcnt[sb], SB_CAP);
            int k0 = chunk * B_EDGES, kend = min(B_EDGES, cnt - k0);
            if (kend > 0) {
                int wv = tid >> 6;
                for (int i = tid; i < FB_PER_SB * 4; i += 256) aux0[i] = 0;
                __syncthreads();
                int base = sb * SB_CAP + k0;
                for (int k = tid; k < kend; k += 256) {
                    int rw = sbA[base + k];
                    unsigned short cl = sbB[base + k];
                    srw[k] = rw; scl[k] = cl;
                    atomicAdd(&aux0[(cl >> 8) * 4 + wv], 1);
                }
                __syncthreads();
                for (int i = tid; i < FB_PER_SB * 4; i += 256) {
                    int c = aux0[i];
                    int gb = sb * FB_PER_SB + (i >> 2);
                    aux1[i] = c ? atomicAdd(&bcur[gb * 16], c) : 0;
                    aux0[i] = 0;
                }
                __syncthreads();
                for (int k = tid; k < kend; k += 256) {
                    int rw = srw[k];
                    unsigned short cl = scl[k];
                    int fb = cl >> 8;
                    int idx = fb * 4 + wv;
                    int rk = atomicAdd(&aux0[idx], 1);
                    int pos = aux1[idx] + rk;
                    int gb = sb * FB_PER_SB + fb;
                    if (pos < (gb + 1) * BCAP) {
                        irA[pos] = rw;
                        irB[pos] = (unsigned char)(cl & 255);
                    }
                }
                __syncthreads();
            }
        }
    }
    gsync(&bars[3], G);

    // ---------- P5: in-bucket sort by node; meta, dinv, fp16 xd ----------
    {
        int* srw = (int*)buf;                   // 4864 ints = 19456B
        unsigned char* scb = buf + 19456;       // 4864 bytes
        float* wsum = (float*)aux1;
        for (int vb = b0; vb < NBKT; vb += G) {
            int base = vb * BCAP;
            int cnt = min(bcur[vb * 16] - base, BCAP);
            aux0[tid] = 0; wsum[tid] = 0.0f; aux3[tid] = 0;
            __syncthreads();
            for (int k = tid; k < cnt; k += 256) {
                int rw = irA[base + k];
                unsigned char c = irB[base + k];
                srw[k] = rw; scb[k] = c;
                atomicAdd(&aux0[c], 1);
                atomicAdd(&wsum[c], (float)(rw & 16383) * (1.0f / 16384.0f));
            }
            __syncthreads();
            int v = aux0[tid];
            aux2[tid] = v;
            __syncthreads();
            for (int d = 1; d < 256; d <<= 1) {
                int u = (tid >= d) ? aux2[tid - d] : 0;
                __syncthreads();
                aux2[tid] += u; __syncthreads();
            }
            int excl = aux2[tid] - v;
            __syncthreads();
            aux2[tid] = excl;
            int node = vb * 256 + tid;
            float dv = rsqrtf(1.0f + wsum[tid]);
            if (node < N) {
                meta[node] = make_int4(base + excl, v, __float_as_int(dv), 0);
                float xv[F_IN];
                #pragma unroll
                for (int j = 0; j < F_IN; ++j) xv[j] = dv * x[(size_t)node * F_IN + j];
                size_t o = (size_t)node * 6;
                xdh[o + 0] = pack_h2(xv[0], xv[1]);
                xdh[o + 1] = pack_h2(xv[2], xv[3]);
                xdh[o + 2] = pack_h2(xv[4], xv[5]);
                xdh[o + 3] = pack_h2(xv[6], xv[7]);
                xdh[o + 4] = pack_h2(xv[8], 0.0f);
                xdh[o + 5] = 0u;
            }
            __syncthreads();
            for (int k = tid; k < cnt; k += 256) {
                int rw = srw[k];
                unsigned char c = scb[k];
                int r = atomicAdd(&aux3[c], 1);
                irA[base + aux2[c] + r] = rw;      // csr4 in place (row<<14|wq)
            }
            __syncthreads();
        }
    }
    gsync(&bars[4], G);

    // ---------- P6: gather layer 1 + fused MLP (4 lanes/node) ----------
    {
        float* sW1 = (float*)buf;                  // 288 floats
        float* sb1 = (float*)(buf + 1152);         // 32 floats
        float* sW2 = (float*)(buf + 1280);         // 224 floats
        for (int t = tid; t < F_IN * F_HID; t += 256) sW1[t] = W1[t];
        if (tid < F_HID) sb1[tid] = b1[tid];
        if (tid < F_HID * F_OUT) sW2[tid] = W2[tid];
        __syncthreads();

        const int NVB = (N * 4 + 255) / 256;
        for (int vb = b0; vb < NVB; vb += G) {
            int t = vb * 256 + tid;
            int i = t >> 2, sub = t & 3;
            if (i < N) {
                int4 m = meta[i];
                float dv = __int_as_float(m.z);
                float acc[F_IN];
                #pragma unroll
                for (int j = 0; j < F_IN; ++j) acc[j] = 0.0f;
                if (sub == 0) {
                    size_t o = (size_t)i * 6;
                    uint2 u01 = *reinterpret_cast<const uint2*>(xdh + o);
                    uint2 u23 = *reinterpret_cast<const uint2*>(xdh + o + 2);
                    unsigned u4 = xdh[o + 4];
                    float2 f0 = unpack_h2(u01.x), f1 = unpack_h2(u01.y),
                           f2 = unpack_h2(u23.x), f3 = unpack_h2(u23.y),
                           f4 = unpack_h2(u4);
                    acc[0] = f0.x; acc[1] = f0.y; acc[2] = f1.x; acc[3] = f1.y;
                    acc[4] = f2.x; acc[5] = f2.y; acc[6] = f3.x; acc[7] = f3.y;
                    acc[8] = f4.x;
                }
                int s = m.x, tend = m.x + m.y;
                for (int e = s + sub; e < tend; e += 4) {
                    int v = nt_load_int(&irA[e]);
                    int r = (int)((unsigned)v >> 14);
                    float wv = (float)(v & 16383) * (1.0f / 16384.0f);
                    size_t o = (size_t)r * 6;
                    uint2 u01 = *reinterpret_cast<const uint2*>(xdh + o);
                    uint2 u23 = *reinterpret_cast<const uint2*>(xdh + o + 2);
                    unsigned u4 = xdh[o + 4];
                    float2 f0 = unpack_h2(u01.x), f1 = unpack_h2(u01.y),
                           f2 = unpack_h2(u23.x), f3 = unpack_h2(u23.y),
                           f4 = unpack_h2(u4);
                    acc[0] = fmaf(wv, f0.x, acc[0]); acc[1] = fmaf(wv, f0.y, acc[1]);
                    acc[2] = fmaf(wv, f1.x, acc[2]); acc[3] = fmaf(wv, f1.y, acc[3]);
                    acc[4] = fmaf(wv, f2.x, acc[4]); acc[5] = fmaf(wv, f2.y, acc[5]);
                    acc[6] = fmaf(wv, f3.x, acc[6]); acc[7] = fmaf(wv, f3.y, acc[7]);
                    acc[8] = fmaf(wv, f4.x, acc[8]);
                }
                #pragma unroll
                for (int d = 1; d < 4; d <<= 1) {
                    #pragma unroll
                    for (int j = 0; j < F_IN; ++j)
                        acc[j] += __shfl_xor(acc[j], d, 4);
                }
                #pragma unroll
                for (int j = 0; j < F_IN; ++j) acc[j] *= dv;

                float o7[F_OUT];
                #pragma unroll
                for (int c = 0; c < F_OUT; ++c) o7[c] = 0.0f;
                int ks = sub * 8;
                #pragma unroll
                for (int k = 0; k < 8; ++k) {
                    float hk = sb1[ks + k];
                    #pragma unroll
                    for (int j = 0; j < F_IN; ++j)
                        hk = fmaf(acc[j], sW1[j * F_HID + ks + k], hk);
                    hk = fmaxf(hk, 0.0f);
                    #pragma unroll
                    for (int c = 0; c < F_OUT; ++c)
                        o7[c] = fmaf(hk, sW2[(ks + k) * F_OUT + c], o7[c]);
                }
                #pragma unroll
                for (int d = 1; d < 4; d <<= 1) {
                    #pragma unroll
                    for (int c = 0; c < F_OUT; ++c)
                        o7[c] += __shfl_xor(o7[c], d, 4);
                }
                float pa = dv * o7[2 * sub];
                float pb = (2 * sub + 1 < F_OUT) ? dv * o7[2 * sub + 1] : 0.0f;
                h2dh[(size_t)i * 4 + sub] = pack_h2(pa, pb);
            }
        }
    }
    gsync(&bars[5], G);

    // ---------- P7: gather layer 2 + bias + log_softmax ----------
    {
        const int NVB = (N * 4 + 255) / 256;
        for (int vb = b0; vb < NVB; vb += G) {
            int t = vb * 256 + tid;
            int i = t >> 2, sub = t & 3;
            if (i >= N) continue;
            int4 m = meta[i];
            float dv = __int_as_float(m.z);
            float acc[F_OUT];
            #pragma unroll
            for (int c = 0; c < F_OUT; ++c) acc[c] = 0.0f;
            if (sub == 0) {
                uint4 h4 = *reinterpret_cast<const uint4*>(h2dh + (size_t)i * 4);
                float2 f0 = unpack_h2(h4.x), f1 = unpack_h2(h4.y),
                       f2 = unpack_h2(h4.z), f3 = unpack_h2(h4.w);
                acc[0] = f0.x; acc[1] = f0.y; acc[2] = f1.x; acc[3] = f1.y;
                acc[4] = f2.x; acc[5] = f2.y; acc[6] = f3.x;
            }
            int s = m.x, tend = m.x + m.y;
            for (int e = s + sub; e < tend; e += 4) {
                int v = nt_load_int(&irA[e]);
                int r = (int)((unsigned)v >> 14);
                float wv = (float)(v & 16383) * (1.0f / 16384.0f);
                uint4 h4 = *reinterpret_cast<const uint4*>(h2dh + (size_t)r * 4);
                float2 f0 = unpack_h2(h4.x), f1 = unpack_h2(h4.y),
                       f2 = unpack_h2(h4.z), f3 = unpack_h2(h4.w);
                acc[0] = fmaf(wv, f0.x, acc[0]); acc[1] = fmaf(wv, f0.y, acc[1]);
                acc[2] = fmaf(wv, f1.x, acc[2]); acc[3] = fmaf(wv, f1.y, acc[3]);
                acc[4] = fmaf(wv, f2.x, acc[4]); acc[5] = fmaf(wv, f2.y, acc[5]);
                acc[6] = fmaf(wv, f3.x, acc[6]);
            }
            #pragma unroll
            for (int d = 1; d < 4; d <<= 1) {
                #pragma unroll
                for (int c = 0; c < F_OUT; ++c)
                    acc[c] += __shfl_xor(acc[c], d, 4);
            }
            float vv[F_OUT];
            float mx = -1e30f;
            #pragma unroll
            for (int c = 0; c < F_OUT; ++c) {
                vv[c] = dv * acc[c] + b2[c];
                mx = fmaxf(mx, vv[c]);
            }
            float ss = 0.0f;
            #pragma unroll
            for (int c = 0; c < F_OUT; ++c) ss += __expf(vv[c] - mx);
            float ls = __logf(ss);
            for (int c = sub; c < F_OUT; c += 4)
                out[(size_t)i * F_OUT + c] = vv[c] - mx - ls;
        }
    }
}

extern "C" void kernel_launch(void* const* d_in, const int* in_sizes, int n_in,
                              void* d_out, int out_size, void* d_ws, size_t ws_size,
                              hipStream_t stream) {
    const float* x  = (const float*)d_in[0];
    const int*   ei = (const int*)  d_in[1];   // [2, E]: row ptr then col ptr
    const float* ew = (const float*)d_in[2];
    const float* W1 = (const float*)d_in[3];
    const float* b1 = (const float*)d_in[4];
    const float* W2 = (const float*)d_in[5];
    const float* b2 = (const float*)d_in[6];
    float* out = (float*)d_out;

    const int N = in_sizes[0] / F_IN;
    const int E = in_sizes[2];
    const int* row = ei;
    const int* col = ei + E;
    const int nblkA = (E + A_EDGES - 1) / A_EDGES;

    // workspace layout (~30.5 MB):
    char* p = (char*)d_ws;
    int*            sbA   = (int*)p;             p += sizeof(int)  * (size_t)NSB * SB_CAP;   // 10.3MB
    unsigned short* sbB   = (unsigned short*)p;  p += sizeof(short)* (size_t)NSB * SB_CAP;   // 5.1MB
    int*            irA   = (int*)p;             p += sizeof(int)  * (size_t)NBKT_PAD * BCAP;// 11.8MB
    unsigned char*  irB   = (unsigned char*)p;   p += (size_t)NBKT_PAD * BCAP;               // 3.0MB
    int*            bcur  = (int*)p;             p += sizeof(int) * (size_t)NBKT_PAD * 16;
    int*            ghist = (int*)p;             p += sizeof(int) * (size_t)NSB * nblkA;
    int*            sbcnt = (int*)p;             p += sizeof(int) * 32;
    int*            bars  = (int*)p;             p += sizeof(int) * 8;
    // overlay on sbA/sbB (dead after P4; written in P5): 8.4MB <= 15.4MB
    int4*     meta = (int4*)d_ws;
    unsigned* xdh  = (unsigned*)(meta + N);
    unsigned* h2dh = xdh + (size_t)N * 6;

    k_init<<<3, 256, 0, stream>>>(bcur, bars);
    k_gcn<<<GRID, 256, 0, stream>>>(row, col, ew, x, W1, b1, W2, b2, out,
                                    sbA, sbB, irA, irB, bcur, ghist, sbcnt, bars,
                                    meta, xdh, h2dh, N, E, nblkA);
}

// Round 13
// 1023.408 us; speedup vs baseline: 1.5419x; 1.5419x over previous
//
#include <hip/hip_runtime.h>
#include <hip/hip_fp16.h>

constexpr int F_IN  = 9;
constexpr int F_HID = 32;
constexpr int F_OUT = 7;

constexpr int SB_SHIFT = 13;
constexpr int SB_NODES = 1 << SB_SHIFT;          // 8192
constexpr int NSB      = 19;                     // ceil(150000/8192)
constexpr int SB_CAP   = 135424;
constexpr int A_EDGES  = 4096;
constexpr int FB_PER_SB= 32;
constexpr int NBKT     = 586;
constexpr int NBKT_PAD = 608;
constexpr int BCAP     = 4864;
constexpr int B_EDGES  = 4096;
constexpr int B_CHUNKS = (SB_CAP + B_EDGES - 1) / B_EDGES;  // 34
constexpr int GRID     = 896;                    // <= 4 blocks/CU * 256 CU

__device__ __forceinline__ int nt_load_int(const int* p) {
    return __builtin_nontemporal_load(p);
}
__device__ __forceinline__ unsigned pack_h2(float a, float b) {
    return (unsigned)__half_as_ushort(__float2half(a)) |
           ((unsigned)__half_as_ushort(__float2half(b)) << 16);
}
__device__ __forceinline__ float2 unpack_h2(unsigned u) {
    return make_float2(__half2float(__ushort_as_half((unsigned short)(u & 0xffffu))),
                       __half2float(__ushort_as_half((unsigned short)(u >> 16))));
}

// software grid barrier. KEY: poll with RELAXED load (cache-bypassing read of
// the coherence point, NO per-poll cache invalidate). Exactly one acquire
// fence after exit. Round-12's ACQUIRE-per-poll invalidated the XCD L2 every
// ~100ns from every waiting block -> 136 GB/s global slowdown.
__device__ __forceinline__ void gsync(int* bar, int nblk) {
    __syncthreads();
    if (threadIdx.x == 0) {
        __threadfence();                       // release: publish this block's writes
        atomicAdd(bar, 1);
        while (__hip_atomic_load(bar, __ATOMIC_RELAXED, __HIP_MEMORY_SCOPE_AGENT) < nblk)
            __builtin_amdgcn_s_sleep(32);
    }
    __syncthreads();
    __threadfence();                           // single acquire: invalidate once
}

__global__ void k_init(int* __restrict__ bcur, int* __restrict__ bars) {
    int i = blockIdx.x * 256 + threadIdx.x;
    if (i < NBKT_PAD) bcur[i * 16] = i * BCAP;
    if (i < 8) bars[i] = 0;
}

__global__ __launch_bounds__(256, 4) void k_gcn(
    const int* __restrict__ row, const int* __restrict__ col,
    const float* __restrict__ w, const float* __restrict__ x,
    const float* __restrict__ W1, const float* __restrict__ b1,
    const float* __restrict__ W2, const float* __restrict__ b2,
    float* __restrict__ out,
    int* __restrict__ sbA, unsigned short* __restrict__ sbB,
    int* __restrict__ irA, unsigned char* __restrict__ irB,
    int* __restrict__ bcur, int* __restrict__ ghist, int* __restrict__ sbcnt,
    int* __restrict__ bars,
    int4* __restrict__ meta, unsigned* __restrict__ xdh, unsigned* __restrict__ h2dh,
    int N, int E, int nblkA)
{
    __shared__ unsigned char buf[24832];       // staging / weights union
    __shared__ int aux0[256];
    __shared__ int aux1[256];
    __shared__ int aux2[256];
    __shared__ int aux3[256];

    const int tid = threadIdx.x;
    const int G   = gridDim.x;
    const int b0  = blockIdx.x;

    // ---------- P1: per-chunk histogram over superbuckets ----------
    for (int vb = b0; vb < nblkA; vb += G) {
        if (tid < NSB) aux0[tid] = 0;
        __syncthreads();
        int t0 = vb * A_EDGES, kend = min(A_EDGES, E - t0);
        for (int k = tid; k < kend; k += 256)
            atomicAdd(&aux0[col[t0 + k] >> SB_SHIFT], 1);
        __syncthreads();
        if (tid < NSB) ghist[(size_t)tid * nblkA + vb] = aux0[tid];
        __syncthreads();
    }
    gsync(&bars[0], G);

    // ---------- P2: exclusive scan of each superbucket row ----------
    for (int s = b0; s < NSB; s += G) {
        int* r = ghist + (size_t)s * nblkA;
        int per = (nblkA + 255) / 256;
        int i0 = tid * per, i1 = min(i0 + per, nblkA);
        int sum = 0;
        for (int i = i0; i < i1; ++i) sum += r[i];
        aux0[tid] = sum; __syncthreads();
        for (int d = 1; d < 256; d <<= 1) {
            int u = (tid >= d) ? aux0[tid - d] : 0;
            __syncthreads();
            aux0[tid] += u; __syncthreads();
        }
        int run = aux0[tid] - sum;
        for (int i = i0; i < i1; ++i) { int v = r[i]; r[i] = run; run += v; }
        if (tid == 255) sbcnt[s] = run;
        __syncthreads();
    }
    gsync(&bars[1], G);

    // ---------- P3: scatter edges to superbuckets (split planes) ----------
    for (int vb = b0; vb < nblkA; vb += G) {
        if (tid < NSB) {
            aux0[tid] = tid * SB_CAP + ghist[(size_t)tid * nblkA + vb];
            aux1[tid] = 0;
        }
        __syncthreads();
        int t0 = vb * A_EDGES, kend = min(A_EDGES, E - t0);
        for (int k = tid; k < kend; k += 256) {
            int e = t0 + k;
            int c = col[e];
            int s = c >> SB_SHIFT;
            int wq = min((int)(w[e] * 16384.0f + 0.5f), 16383);
            int rw = (row[e] << 14) | wq;
            int rk = atomicAdd(&aux1[s], 1);
            int pos = aux0[s] + rk;
            if (pos < (s + 1) * SB_CAP) {
                sbA[pos] = rw;
                sbB[pos] = (unsigned short)(c & (SB_NODES - 1));
            }
        }
        __syncthreads();
    }
    gsync(&bars[2], G);

    // ---------- P4: superbucket -> 32 final buckets ----------
    {
        int* srw = (int*)buf;                              // 4096 ints
        unsigned short* scl = (unsigned short*)(buf + 16384); // 4096 u16
        for (int vb = b0; vb < NSB * B_CHUNKS; vb += G) {
            int sb = vb / B_CHUNKS, chunk = vb % B_CHUNKS;
            int cnt = min(sbcnt[sb], SB_CAP);
            int k0 = chunk * B_EDGES, kend = min(B_EDGES, cnt - k0);
            if (kend > 0) {
                int wv = tid >> 6;
                for (int i = tid; i < FB_PER_SB * 4; i += 256) aux0[i] = 0;
                __syncthreads();
                int base = sb * SB_CAP + k0;
                for (int k = tid; k < kend; k += 256) {
                    int rw = sbA[base + k];
                    unsigned short cl = sbB[base + k];
                    srw[k] = rw; scl[k] = cl;
                    atomicAdd(&aux0[(cl >> 8) * 4 + wv], 1);
                }
                __syncthreads();
                for (int i = tid; i < FB_PER_SB * 4; i += 256) {
                    int c = aux0[i];
                    int gb = sb * FB_PER_SB + (i >> 2);
                    aux1[i] = c ? atomicAdd(&bcur[gb * 16], c) : 0;
                    aux0[i] = 0;
                }
                __syncthreads();
                for (int k = tid; k < kend; k += 256) {
                    int rw = srw[k];
                    unsigned short cl = scl[k];
                    int fb = cl >> 8;
                    int idx = fb * 4 + wv;
                    int rk = atomicAdd(&aux0[idx], 1);
                    int pos = aux1[idx] + rk;
                    int gb = sb * FB_PER_SB + fb;
                    if (pos < (gb + 1) * BCAP) {
                        irA[pos] = rw;
                        irB[pos] = (unsigned char)(cl & 255);
                    }
                }
                __syncthreads();
            }
        }
    }
    gsync(&bars[3], G);

    // ---------- P5: in-bucket sort by node; meta, dinv, fp16 xd ----------
    {
        int* srw = (int*)buf;                   // 4864 ints = 19456B
        unsigned char* scb = buf + 19456;       // 4864 bytes
        float* wsum = (float*)aux1;
        for (int vb = b0; vb < NBKT; vb += G) {
            int base = vb * BCAP;
            int cnt = min(bcur[vb * 16] - base, BCAP);
            aux0[tid] = 0; wsum[tid] = 0.0f; aux3[tid] = 0;
            __syncthreads();
            for (int k = tid; k < cnt; k += 256) {
                int rw = irA[base + k];
                unsigned char c = irB[base + k];
                srw[k] = rw; scb[k] = c;
                atomicAdd(&aux0[c], 1);
                atomicAdd(&wsum[c], (float)(rw & 16383) * (1.0f / 16384.0f));
            }
            __syncthreads();
            int v = aux0[tid];
            aux2[tid] = v;
            __syncthreads();
            for (int d = 1; d < 256; d <<= 1) {
                int u = (tid >= d) ? aux2[tid - d] : 0;
                __syncthreads();
                aux2[tid] += u; __syncthreads();
            }
            int excl = aux2[tid] - v;
            __syncthreads();
            aux2[tid] = excl;
            int node = vb * 256 + tid;
            float dv = rsqrtf(1.0f + wsum[tid]);
            if (node < N) {
                meta[node] = make_int4(base + excl, v, __float_as_int(dv), 0);
                float xv[F_IN];
                #pragma unroll
                for (int j = 0; j < F_IN; ++j) xv[j] = dv * x[(size_t)node * F_IN + j];
                size_t o = (size_t)node * 6;
                xdh[o + 0] = pack_h2(xv[0], xv[1]);
                xdh[o + 1] = pack_h2(xv[2], xv[3]);
                xdh[o + 2] = pack_h2(xv[4], xv[5]);
                xdh[o + 3] = pack_h2(xv[6], xv[7]);
                xdh[o + 4] = pack_h2(xv[8], 0.0f);
                xdh[o + 5] = 0u;
            }
            __syncthreads();
            for (int k = tid; k < cnt; k += 256) {
                int rw = srw[k];
                unsigned char c = scb[k];
                int r = atomicAdd(&aux3[c], 1);
                irA[base + aux2[c] + r] = rw;      // csr4 in place (row<<14|wq)
            }
            __syncthreads();
        }
    }
    gsync(&bars[4], G);

    // ---------- P6: gather layer 1 + fused MLP (4 lanes/node) ----------
    {
        float* sW1 = (float*)buf;                  // 288 floats
        float* sb1 = (float*)(buf + 1152);         // 32 floats
        float* sW2 = (float*)(buf + 1280);         // 224 floats
        for (int t = tid; t < F_IN * F_HID; t += 256) sW1[t] = W1[t];
        if (tid < F_HID) sb1[tid] = b1[tid];
        if (tid < F_HID * F_OUT) sW2[tid] = W2[tid];
        __syncthreads();

        const int NVB = (N * 4 + 255) / 256;
        for (int vb = b0; vb < NVB; vb += G) {
            int t = vb * 256 + tid;
            int i = t >> 2, sub = t & 3;
            if (i < N) {
                int4 m = meta[i];
                float dv = __int_as_float(m.z);
                float acc[F_IN];
                #pragma unroll
                for (int j = 0; j < F_IN; ++j) acc[j] = 0.0f;
                if (sub == 0) {
                    size_t o = (size_t)i * 6;
                    uint2 u01 = *reinterpret_cast<const uint2*>(xdh + o);
                    uint2 u23 = *reinterpret_cast<const uint2*>(xdh + o + 2);
                    unsigned u4 = xdh[o + 4];
                    float2 f0 = unpack_h2(u01.x), f1 = unpack_h2(u01.y),
                           f2 = unpack_h2(u23.x), f3 = unpack_h2(u23.y),
                           f4 = unpack_h2(u4);
                    acc[0] = f0.x; acc[1] = f0.y; acc[2] = f1.x; acc[3] = f1.y;
                    acc[4] = f2.x; acc[5] = f2.y; acc[6] = f3.x; acc[7] = f3.y;
                    acc[8] = f4.x;
                }
                int s = m.x, tend = m.x + m.y;
                for (int e = s + sub; e < tend; e += 4) {
                    int v = nt_load_int(&irA[e]);
                    int r = (int)((unsigned)v >> 14);
                    float wv = (float)(v & 16383) * (1.0f / 16384.0f);
                    size_t o = (size_t)r * 6;
                    uint2 u01 = *reinterpret_cast<const uint2*>(xdh + o);
                    uint2 u23 = *reinterpret_cast<const uint2*>(xdh + o + 2);
                    unsigned u4 = xdh[o + 4];
                    float2 f0 = unpack_h2(u01.x), f1 = unpack_h2(u01.y),
                           f2 = unpack_h2(u23.x), f3 = unpack_h2(u23.y),
                           f4 = unpack_h2(u4);
                    acc[0] = fmaf(wv, f0.x, acc[0]); acc[1] = fmaf(wv, f0.y, acc[1]);
                    acc[2] = fmaf(wv, f1.x, acc[2]); acc[3] = fmaf(wv, f1.y, acc[3]);
                    acc[4] = fmaf(wv, f2.x, acc[4]); acc[5] = fmaf(wv, f2.y, acc[5]);
                    acc[6] = fmaf(wv, f3.x, acc[6]); acc[7] = fmaf(wv, f3.y, acc[7]);
                    acc[8] = fmaf(wv, f4.x, acc[8]);
                }
                #pragma unroll
                for (int d = 1; d < 4; d <<= 1) {
                    #pragma unroll
                    for (int j = 0; j < F_IN; ++j)
                        acc[j] += __shfl_xor(acc[j], d, 4);
                }
                #pragma unroll
                for (int j = 0; j < F_IN; ++j) acc[j] *= dv;

                float o7[F_OUT];
                #pragma unroll
                for (int c = 0; c < F_OUT; ++c) o7[c] = 0.0f;
                int ks = sub * 8;
                #pragma unroll
                for (int k = 0; k < 8; ++k) {
                    float hk = sb1[ks + k];
                    #pragma unroll
                    for (int j = 0; j < F_IN; ++j)
                        hk = fmaf(acc[j], sW1[j * F_HID + ks + k], hk);
                    hk = fmaxf(hk, 0.0f);
                    #pragma unroll
                    for (int c = 0; c < F_OUT; ++c)
                        o7[c] = fmaf(hk, sW2[(ks + k) * F_OUT + c], o7[c]);
                }
                #pragma unroll
                for (int d = 1; d < 4; d <<= 1) {
                    #pragma unroll
                    for (int c = 0; c < F_OUT; ++c)
                        o7[c] += __shfl_xor(o7[c], d, 4);
                }
                float pa = dv * o7[2 * sub];
                float pb = (2 * sub + 1 < F_OUT) ? dv * o7[2 * sub + 1] : 0.0f;
                h2dh[(size_t)i * 4 + sub] = pack_h2(pa, pb);
            }
        }
    }
    gsync(&bars[5], G);

    // ---------- P7: gather layer 2 + bias + log_softmax ----------
    {
        const int NVB = (N * 4 + 255) / 256;
        for (int vb = b0; vb < NVB; vb += G) {
            int t = vb * 256 + tid;
            int i = t >> 2, sub = t & 3;
            if (i >= N) continue;
            int4 m = meta[i];
            float dv = __int_as_float(m.z);
            float acc[F_OUT];
            #pragma unroll
            for (int c = 0; c < F_OUT; ++c) acc[c] = 0.0f;
            if (sub == 0) {
                uint4 h4 = *reinterpret_cast<const uint4*>(h2dh + (size_t)i * 4);
                float2 f0 = unpack_h2(h4.x), f1 = unpack_h2(h4.y),
                       f2 = unpack_h2(h4.z), f3 = unpack_h2(h4.w);
                acc[0] = f0.x; acc[1] = f0.y; acc[2] = f1.x; acc[3] = f1.y;
                acc[4] = f2.x; acc[5] = f2.y; acc[6] = f3.x;
            }
            int s = m.x, tend = m.x + m.y;
            for (int e = s + sub; e < tend; e += 4) {
                int v = nt_load_int(&irA[e]);
                int r = (int)((unsigned)v >> 14);
                float wv = (float)(v & 16383) * (1.0f / 16384.0f);
                uint4 h4 = *reinterpret_cast<const uint4*>(h2dh + (size_t)r * 4);
                float2 f0 = unpack_h2(h4.x), f1 = unpack_h2(h4.y),
                       f2 = unpack_h2(h4.z), f3 = unpack_h2(h4.w);
                acc[0] = fmaf(wv, f0.x, acc[0]); acc[1] = fmaf(wv, f0.y, acc[1]);
                acc[2] = fmaf(wv, f1.x, acc[2]); acc[3] = fmaf(wv, f1.y, acc[3]);
                acc[4] = fmaf(wv, f2.x, acc[4]); acc[5] = fmaf(wv, f2.y, acc[5]);
                acc[6] = fmaf(wv, f3.x, acc[6]);
            }
            #pragma unroll
            for (int d = 1; d < 4; d <<= 1) {
                #pragma unroll
                for (int c = 0; c < F_OUT; ++c)
                    acc[c] += __shfl_xor(acc[c], d, 4);
            }
            float vv[F_OUT];
            float mx = -1e30f;
            #pragma unroll
            for (int c = 0; c < F_OUT; ++c) {
                vv[c] = dv * acc[c] + b2[c];
                mx = fmaxf(mx, vv[c]);
            }
            float ss = 0.0f;
            #pragma unroll
            for (int c = 0; c < F_OUT; ++c) ss += __expf(vv[c] - mx);
            float ls = __logf(ss);
            for (int c = sub; c < F_OUT; c += 4)
                out[(size_t)i * F_OUT + c] = vv[c] - mx - ls;
        }
    }
}

extern "C" void kernel_launch(void* const* d_in, const int* in_sizes, int n_in,
                              void* d_out, int out_size, void* d_ws, size_t ws_size,
                              hipStream_t stream) {
    const float* x  = (const float*)d_in[0];
    const int*   ei = (const int*)  d_in[1];   // [2, E]: row ptr then col ptr
    const float* ew = (const float*)d_in[2];
    const float* W1 = (const float*)d_in[3];
    const float* b1 = (const float*)d_in[4];
    const float* W2 = (const float*)d_in[5];
    const float* b2 = (const float*)d_in[6];
    float* out = (float*)d_out;

    const int N = in_sizes[0] / F_IN;
    const int E = in_sizes[2];
    const int* row = ei;
    const int* col = ei + E;
    const int nblkA = (E + A_EDGES - 1) / A_EDGES;

    // workspace layout (~30.5 MB):
    char* p = (char*)d_ws;
    int*            sbA   = (int*)p;             p += sizeof(int)  * (size_t)NSB * SB_CAP;   // 10.3MB
    unsigned short* sbB   = (unsigned short*)p;  p += sizeof(short)* (size_t)NSB * SB_CAP;   // 5.1MB
    int*            irA   = (int*)p;             p += sizeof(int)  * (size_t)NBKT_PAD * BCAP;// 11.8MB
    unsigned char*  irB   = (unsigned char*)p;   p += (size_t)NBKT_PAD * BCAP;               // 3.0MB
    int*            bcur  = (int*)p;             p += sizeof(int) * (size_t)NBKT_PAD * 16;
    int*            ghist = (int*)p;             p += sizeof(int) * (size_t)NSB * nblkA;
    int*            sbcnt = (int*)p;             p += sizeof(int) * 32;
    int*            bars  = (int*)p;             p += sizeof(int) * 8;
    // overlay on sbA/sbB (dead after P4; written in P5): 8.4MB <= 15.4MB
    int4*     meta = (int4*)d_ws;
    unsigned* xdh  = (unsigned*)(meta + N);
    unsigned* h2dh = xdh + (size_t)N * 6;

    k_init<<<3, 256, 0, stream>>>(bcur, bars);
    k_gcn<<<GRID, 256, 0, stream>>>(row, col, ew, x, W1, b1, W2, b2, out,
                                    sbA, sbB, irA, irB, bcur, ghist, sbcnt, bars,
                                    meta, xdh, h2dh, N, E, nblkA);
}

// Round 14
// 134.259 us; speedup vs baseline: 11.7532x; 7.6226x over previous
//
#include <hip/hip_runtime.h>
#include <hip/hip_fp16.h>

constexpr int F_IN  = 9;
constexpr int F_HID = 32;
constexpr int F_OUT = 7;

constexpr int NBKT   = 586;      // ceil(150000/256) buckets of 256 nodes
constexpr int BCAP   = 4864;     // mean 4096 + 12 sigma
constexpr int CHUNK  = 4096;     // edges per hist/scat block

__device__ __forceinline__ int nt_load_int(const int* p) {
    return __builtin_nontemporal_load(p);
}
__device__ __forceinline__ unsigned pack_h2(float a, float b) {
    return (unsigned)__half_as_ushort(__float2half(a)) |
           ((unsigned)__half_as_ushort(__float2half(b)) << 16);
}
__device__ __forceinline__ float2 unpack_h2(unsigned u) {
    return make_float2(__half2float(__ushort_as_half((unsigned short)(u & 0xffffu))),
                       __half2float(__ushort_as_half((unsigned short)(u >> 16))));
}

// ---------- 1: per-chunk histogram over the 586 final buckets ----------
__global__ __launch_bounds__(256) void k_hist(
    const int* __restrict__ col, int* __restrict__ ghist, int E)
{
    __shared__ int h[NBKT];
    const int tid = threadIdx.x;
    for (int i = tid; i < NBKT; i += 256) h[i] = 0;
    __syncthreads();
    const int t0 = blockIdx.x * CHUNK;
    const int kend = min(CHUNK, E - t0);
    for (int k = tid; k < kend; k += 256)
        atomicAdd(&h[col[t0 + k] >> 8], 1);
    __syncthreads();
    int* g = ghist + (size_t)blockIdx.x * NBKT;
    for (int i = tid; i < NBKT; i += 256) g[i] = h[i];   // coalesced row
}

// ---------- 2: per-bucket exclusive scan down the chunk axis ----------
__global__ __launch_bounds__(256) void k_scan(
    int* __restrict__ ghist, int* __restrict__ cnt, int nchunk)
{
    __shared__ int sc[256];
    const int b = blockIdx.x, tid = threadIdx.x;
    const int per = (nchunk + 255) / 256;
    const int i0 = tid * per, i1 = min(i0 + per, nchunk);

    int sum = 0;
    for (int i = i0; i < i1; ++i) sum += ghist[(size_t)i * NBKT + b];
    sc[tid] = sum; __syncthreads();
    for (int d = 1; d < 256; d <<= 1) {
        int u = (tid >= d) ? sc[tid - d] : 0;
        __syncthreads();
        sc[tid] += u; __syncthreads();
    }
    int run = sc[tid] - sum;                 // exclusive base for this thread
    for (int i = i0; i < i1; ++i) {
        int v = ghist[(size_t)i * NBKT + b];
        ghist[(size_t)i * NBKT + b] = run;
        run += v;
    }
    if (tid == 255) cnt[b] = run;            // total edges in bucket b
}

// ---------- 3: scatter edges straight into final bucket regions ----------
__global__ __launch_bounds__(256) void k_scat(
    const int* __restrict__ row, const int* __restrict__ col,
    const float* __restrict__ w, const int* __restrict__ ghist,
    int2* __restrict__ irec, int E)
{
    __shared__ int sbase[NBKT];
    __shared__ int scur[NBKT];
    const int tid = threadIdx.x;
    const int* g = ghist + (size_t)blockIdx.x * NBKT;
    for (int i = tid; i < NBKT; i += 256) { sbase[i] = g[i]; scur[i] = 0; }
    __syncthreads();
    const int t0 = blockIdx.x * CHUNK;
    const int kend = min(CHUNK, E - t0);
    for (int k = tid; k < kend; k += 256) {
        int e = t0 + k;
        int c = col[e];
        int b = c >> 8;
        int wq = min((int)(w[e] * 16384.0f + 0.5f), 16383);
        int rk = atomicAdd(&scur[b], 1);
        int pos = b * BCAP + sbase[b] + rk;
        if (pos < (b + 1) * BCAP)            // guard (never trips)
            irec[pos] = make_int2((row[e] << 14) | wq, c & 255);
    }
}

// ---------- 4: in-bucket sort by node; csr4 (separate), meta, fp16 xd ------
__global__ __launch_bounds__(256) void k_sortbucket(
    const int2* __restrict__ irec, int* __restrict__ csr4,
    const int* __restrict__ cnt, const float* __restrict__ x,
    int4* __restrict__ meta, unsigned* __restrict__ xdh, int N)
{
    __shared__ int           srw[BCAP];      // 19456 B
    __shared__ unsigned char scb[BCAP];      // 4864 B
    __shared__ int   hist[256];
    __shared__ float wsum[256];
    __shared__ int   nbase[256];
    __shared__ int   scur[256];

    const int b    = blockIdx.x;
    const int tid  = threadIdx.x;
    const int base = b * BCAP;
    const int c_n  = min(cnt[b], BCAP);

    hist[tid] = 0; wsum[tid] = 0.0f; scur[tid] = 0;
    __syncthreads();

    for (int k = tid; k < c_n; k += 256) {
        int2 rc = irec[base + k];
        srw[k] = rc.x;
        unsigned char c = (unsigned char)(rc.y & 255);
        scb[k] = c;
        atomicAdd(&hist[c], 1);
        atomicAdd(&wsum[c], (float)(rc.x & 16383) * (1.0f / 16384.0f));
    }
    __syncthreads();

    int v = hist[tid];
    nbase[tid] = v;
    __syncthreads();
    for (int d = 1; d < 256; d <<= 1) {
        int u = (tid >= d) ? nbase[tid - d] : 0;
        __syncthreads();
        nbase[tid] += u;
        __syncthreads();
    }
    int excl = nbase[tid] - v;
    __syncthreads();
    nbase[tid] = excl;

    int node = b * 256 + tid;
    float dv = rsqrtf(1.0f + wsum[tid]);
    if (node < N) {
        meta[node] = make_int4(base + excl, v, __float_as_int(dv), 0);
        float xv[F_IN];
        #pragma unroll
        for (int j = 0; j < F_IN; ++j) xv[j] = dv * x[(size_t)node * F_IN + j];
        size_t o = (size_t)node * 6;
        xdh[o + 0] = pack_h2(xv[0], xv[1]);
        xdh[o + 1] = pack_h2(xv[2], xv[3]);
        xdh[o + 2] = pack_h2(xv[4], xv[5]);
        xdh[o + 3] = pack_h2(xv[6], xv[7]);
        xdh[o + 4] = pack_h2(xv[8], 0.0f);
        xdh[o + 5] = 0u;
    }
    __syncthreads();

    for (int k = tid; k < c_n; k += 256) {
        int rw = srw[k];
        unsigned char c = scb[k];
        int r = atomicAdd(&scur[c], 1);
        csr4[base + nbase[c] + r] = rw;      // (row<<14)|wq, grouped by node
    }
}

// -------- 5: gather layer 1 + fused MLP (4 lanes/node, fp16 tables) --------
__global__ __launch_bounds__(256) void k_g1mlp(
    const int* __restrict__ csr4, const int4* __restrict__ meta,
    const unsigned* __restrict__ xdh,
    const float* __restrict__ W1, const float* __restrict__ b1,
    const float* __restrict__ W2, unsigned* __restrict__ h2dh, int N)
{
    __shared__ float sW1[F_IN * F_HID];
    __shared__ float sb1[F_HID];
    __shared__ float sW2[F_HID * F_OUT];
    for (int t = threadIdx.x; t < F_IN * F_HID; t += 256) sW1[t] = W1[t];
    for (int t = threadIdx.x; t < F_HID;        t += 256) sb1[t] = b1[t];
    for (int t = threadIdx.x; t < F_HID * F_OUT; t += 256) sW2[t] = W2[t];
    __syncthreads();

    int t   = blockIdx.x * 256 + threadIdx.x;
    int i   = t >> 2;
    int sub = t & 3;
    if (i >= N) return;
    int4 m = meta[i];
    float dv = __int_as_float(m.z);

    float acc[F_IN];
    #pragma unroll
    for (int j = 0; j < F_IN; ++j) acc[j] = 0.0f;
    if (sub == 0) {
        size_t o = (size_t)i * 6;
        uint2 u01 = *reinterpret_cast<const uint2*>(xdh + o);
        uint2 u23 = *reinterpret_cast<const uint2*>(xdh + o + 2);
        unsigned u4 = xdh[o + 4];
        float2 f0 = unpack_h2(u01.x), f1 = unpack_h2(u01.y),
               f2 = unpack_h2(u23.x), f3 = unpack_h2(u23.y),
               f4 = unpack_h2(u4);
        acc[0] = f0.x; acc[1] = f0.y; acc[2] = f1.x; acc[3] = f1.y;
        acc[4] = f2.x; acc[5] = f2.y; acc[6] = f3.x; acc[7] = f3.y;
        acc[8] = f4.x;
    }
    int s = m.x, tend = m.x + m.y;
    for (int e = s + sub; e < tend; e += 4) {
        int v = nt_load_int(&csr4[e]);
        int r = (int)((unsigned)v >> 14);
        float wv = (float)(v & 16383) * (1.0f / 16384.0f);
        size_t o = (size_t)r * 6;
        uint2 u01 = *reinterpret_cast<const uint2*>(xdh + o);
        uint2 u23 = *reinterpret_cast<const uint2*>(xdh + o + 2);
        unsigned u4 = xdh[o + 4];
        float2 f0 = unpack_h2(u01.x), f1 = unpack_h2(u01.y),
               f2 = unpack_h2(u23.x), f3 = unpack_h2(u23.y),
               f4 = unpack_h2(u4);
        acc[0] = fmaf(wv, f0.x, acc[0]); acc[1] = fmaf(wv, f0.y, acc[1]);
        acc[2] = fmaf(wv, f1.x, acc[2]); acc[3] = fmaf(wv, f1.y, acc[3]);
        acc[4] = fmaf(wv, f2.x, acc[4]); acc[5] = fmaf(wv, f2.y, acc[5]);
        acc[6] = fmaf(wv, f3.x, acc[6]); acc[7] = fmaf(wv, f3.y, acc[7]);
        acc[8] = fmaf(wv, f4.x, acc[8]);
    }
    #pragma unroll
    for (int d = 1; d < 4; d <<= 1) {
        #pragma unroll
        for (int j = 0; j < F_IN; ++j)
            acc[j] += __shfl_xor(acc[j], d, 4);
    }
    #pragma unroll
    for (int j = 0; j < F_IN; ++j) acc[j] *= dv;

    float o7[F_OUT];
    #pragma unroll
    for (int c = 0; c < F_OUT; ++c) o7[c] = 0.0f;
    int ks = sub * 8;
    #pragma unroll
    for (int k = 0; k < 8; ++k) {
        float hk = sb1[ks + k];
        #pragma unroll
        for (int j = 0; j < F_IN; ++j) hk = fmaf(acc[j], sW1[j * F_HID + ks + k], hk);
        hk = fmaxf(hk, 0.0f);
        #pragma unroll
        for (int c = 0; c < F_OUT; ++c) o7[c] = fmaf(hk, sW2[(ks + k) * F_OUT + c], o7[c]);
    }
    #pragma unroll
    for (int d = 1; d < 4; d <<= 1) {
        #pragma unroll
        for (int c = 0; c < F_OUT; ++c)
            o7[c] += __shfl_xor(o7[c], d, 4);
    }
    float pa = dv * o7[2 * sub];
    float pb = (2 * sub + 1 < F_OUT) ? dv * o7[2 * sub + 1] : 0.0f;
    h2dh[(size_t)i * 4 + sub] = pack_h2(pa, pb);
}

// -------- 6: gather layer 2 + bias + log_softmax (4 lanes/node) --------
__global__ __launch_bounds__(256) void k_g2ls(
    const int* __restrict__ csr4, const int4* __restrict__ meta,
    const unsigned* __restrict__ h2dh, const float* __restrict__ b2,
    float* __restrict__ out, int N)
{
    int t   = blockIdx.x * 256 + threadIdx.x;
    int i   = t >> 2;
    int sub = t & 3;
    if (i >= N) return;
    int4 m = meta[i];
    float dv = __int_as_float(m.z);

    float acc[F_OUT];
    #pragma unroll
    for (int c = 0; c < F_OUT; ++c) acc[c] = 0.0f;
    if (sub == 0) {
        uint4 h4 = *reinterpret_cast<const uint4*>(h2dh + (size_t)i * 4);
        float2 f0 = unpack_h2(h4.x), f1 = unpack_h2(h4.y),
               f2 = unpack_h2(h4.z), f3 = unpack_h2(h4.w);
        acc[0] = f0.x; acc[1] = f0.y; acc[2] = f1.x; acc[3] = f1.y;
        acc[4] = f2.x; acc[5] = f2.y; acc[6] = f3.x;
    }
    int s = m.x, tend = m.x + m.y;
    for (int e = s + sub; e < tend; e += 4) {
        int v = nt_load_int(&csr4[e]);
        int r = (int)((unsigned)v >> 14);
        float wv = (float)(v & 16383) * (1.0f / 16384.0f);
        uint4 h4 = *reinterpret_cast<const uint4*>(h2dh + (size_t)r * 4);
        float2 f0 = unpack_h2(h4.x), f1 = unpack_h2(h4.y),
               f2 = unpack_h2(h4.z), f3 = unpack_h2(h4.w);
        acc[0] = fmaf(wv, f0.x, acc[0]); acc[1] = fmaf(wv, f0.y, acc[1]);
        acc[2] = fmaf(wv, f1.x, acc[2]); acc[3] = fmaf(wv, f1.y, acc[3]);
        acc[4] = fmaf(wv, f2.x, acc[4]); acc[5] = fmaf(wv, f2.y, acc[5]);
        acc[6] = fmaf(wv, f3.x, acc[6]);
    }
    #pragma unroll
    for (int d = 1; d < 4; d <<= 1) {
        #pragma unroll
        for (int c = 0; c < F_OUT; ++c)
            acc[c] += __shfl_xor(acc[c], d, 4);
    }

    float vv[F_OUT];
    float mx = -1e30f;
    #pragma unroll
    for (int c = 0; c < F_OUT; ++c) {
        vv[c] = dv * acc[c] + b2[c];
        mx = fmaxf(mx, vv[c]);
    }
    float ss = 0.0f;
    #pragma unroll
    for (int c = 0; c < F_OUT; ++c) ss += __expf(vv[c] - mx);
    float ls = __logf(ss);
    for (int c = sub; c < F_OUT; c += 4)
        out[(size_t)i * F_OUT + c] = vv[c] - mx - ls;
}

extern "C" void kernel_launch(void* const* d_in, const int* in_sizes, int n_in,
                              void* d_out, int out_size, void* d_ws, size_t ws_size,
                              hipStream_t stream) {
    const float* x  = (const float*)d_in[0];
    const int*   ei = (const int*)  d_in[1];   // [2, E]: row ptr then col ptr
    const float* ew = (const float*)d_in[2];
    const float* W1 = (const float*)d_in[3];
    const float* b1 = (const float*)d_in[4];
    const float* W2 = (const float*)d_in[5];
    const float* b2 = (const float*)d_in[6];
    float* out = (float*)d_out;

    const int N = in_sizes[0] / F_IN;
    const int E = in_sizes[2];
    const int* row = ei;
    const int* col = ei + E;
    const int nchunk = (E + CHUNK - 1) / CHUNK;

    // workspace (~44 MB, no overlays, no aliasing):
    char* p = (char*)d_ws;
    int2*     irec  = (int2*)p;      p += sizeof(int2) * (size_t)NBKT * BCAP;   // 22.8MB
    int*      csr4  = (int*)p;       p += sizeof(int)  * (size_t)NBKT * BCAP;   // 11.4MB
    int4*     meta  = (int4*)p;      p += sizeof(int4) * (size_t)N;             // 2.4MB
    unsigned* xdh   = (unsigned*)p;  p += sizeof(unsigned) * (size_t)N * 6;     // 3.6MB
    unsigned* h2dh  = (unsigned*)p;  p += sizeof(unsigned) * (size_t)N * 4;     // 2.4MB
    int*      ghist = (int*)p;       p += sizeof(int) * (size_t)nchunk * NBKT;  // 1.4MB
    int*      cnt   = (int*)p;       p += sizeof(int) * NBKT;

    const int gN4 = (4 * N + 255) / 256;

    k_hist      <<<nchunk, 256, 0, stream>>>(col, ghist, E);
    k_scan      <<<NBKT, 256, 0, stream>>>(ghist, cnt, nchunk);
    k_scat      <<<nchunk, 256, 0, stream>>>(row, col, ew, ghist, irec, E);
    k_sortbucket<<<NBKT, 256, 0, stream>>>(irec, csr4, cnt, x, meta, xdh, N);
    k_g1mlp     <<<gN4, 256, 0, stream>>>(csr4, meta, xdh, W1, b1, W2, h2dh, N);
    k_g2ls      <<<gN4, 256, 0, stream>>>(csr4, meta, h2dh, b2, out, N);
}

// Round 15
// 133.845 us; speedup vs baseline: 11.7896x; 1.0031x over previous
//
#include <hip/hip_runtime.h>
#include <hip/hip_fp16.h>

constexpr int F_IN  = 9;
constexpr int F_HID = 32;
constexpr int F_OUT = 7;

constexpr int NBKT   = 586;      // ceil(150000/256) buckets of 256 nodes
constexpr int BCAP   = 4864;     // mean 4096 + 12 sigma
constexpr int CHUNK  = 4096;     // edges per hist/scat block

__device__ __forceinline__ int nt_load_int(const int* p) {
    return __builtin_nontemporal_load(p);
}
__device__ __forceinline__ unsigned pack_h2(float a, float b) {
    return (unsigned)__half_as_ushort(__float2half(a)) |
           ((unsigned)__half_as_ushort(__float2half(b)) << 16);
}
__device__ __forceinline__ float2 unpack_h2(unsigned u) {
    return make_float2(__half2float(__ushort_as_half((unsigned short)(u & 0xffffu))),
                       __half2float(__ushort_as_half((unsigned short)(u >> 16))));
}

// ---------- 1: per-chunk histogram over the 586 final buckets ----------
__global__ __launch_bounds__(1024) void k_hist(
    const int* __restrict__ col, int* __restrict__ ghist, int E)
{
    __shared__ int h[NBKT];
    const int tid = threadIdx.x;
    for (int i = tid; i < NBKT; i += 1024) h[i] = 0;
    __syncthreads();
    const int t0 = blockIdx.x * CHUNK;
    const int kend = min(CHUNK, E - t0);
    for (int k = tid; k < kend; k += 1024)
        atomicAdd(&h[col[t0 + k] >> 8], 1);
    __syncthreads();
    int* g = ghist + (size_t)blockIdx.x * NBKT;
    for (int i = tid; i < NBKT; i += 1024) g[i] = h[i];   // coalesced row
}

// ---------- 2: per-bucket exclusive scan down the chunk axis ----------
__global__ __launch_bounds__(256) void k_scan(
    int* __restrict__ ghist, int* __restrict__ cnt, int nchunk)
{
    __shared__ int sc[256];
    const int b = blockIdx.x, tid = threadIdx.x;
    const int per = (nchunk + 255) / 256;
    const int i0 = tid * per, i1 = min(i0 + per, nchunk);

    int sum = 0;
    for (int i = i0; i < i1; ++i) sum += ghist[(size_t)i * NBKT + b];
    sc[tid] = sum; __syncthreads();
    for (int d = 1; d < 256; d <<= 1) {
        int u = (tid >= d) ? sc[tid - d] : 0;
        __syncthreads();
        sc[tid] += u; __syncthreads();
    }
    int run = sc[tid] - sum;                 // exclusive base for this thread
    for (int i = i0; i < i1; ++i) {
        int v = ghist[(size_t)i * NBKT + b];
        ghist[(size_t)i * NBKT + b] = run;
        run += v;
    }
    if (tid == 255) cnt[b] = run;            // total edges in bucket b
}

// ---------- 3: scatter edges straight into final bucket regions ----------
__global__ __launch_bounds__(1024) void k_scat(
    const int* __restrict__ row, const int* __restrict__ col,
    const float* __restrict__ w, const int* __restrict__ ghist,
    int2* __restrict__ irec, int E)
{
    __shared__ int sbase[NBKT];
    __shared__ int scur[NBKT];
    const int tid = threadIdx.x;
    const int* g = ghist + (size_t)blockIdx.x * NBKT;
    for (int i = tid; i < NBKT; i += 1024) { sbase[i] = g[i]; scur[i] = 0; }
    __syncthreads();
    const int t0 = blockIdx.x * CHUNK;
    const int kend = min(CHUNK, E - t0);
    for (int k = tid; k < kend; k += 1024) {
        int e = t0 + k;
        int c = col[e];
        int b = c >> 8;
        int wq = min((int)(w[e] * 16384.0f + 0.5f), 16383);
        int rk = atomicAdd(&scur[b], 1);
        int pos = b * BCAP + sbase[b] + rk;
        if (pos < (b + 1) * BCAP)            // guard (never trips)
            irec[pos] = make_int2((row[e] << 14) | wq, c & 255);
    }
}

// ---------- 4: in-bucket sort by node; csr4 (separate), meta, fp16 xd ------
__global__ __launch_bounds__(1024) void k_sortbucket(
    const int2* __restrict__ irec, int* __restrict__ csr4,
    const int* __restrict__ cnt, const float* __restrict__ x,
    int4* __restrict__ meta, unsigned* __restrict__ xdh, int N)
{
    __shared__ int           srw[BCAP];      // 19456 B
    __shared__ unsigned char scb[BCAP];      // 4864 B
    __shared__ int   hist[256];
    __shared__ float wsum[256];
    __shared__ int   nbase[256];
    __shared__ int   scur[256];

    const int b    = blockIdx.x;
    const int tid  = threadIdx.x;
    const int base = b * BCAP;
    const int c_n  = min(cnt[b], BCAP);

    if (tid < 256) { hist[tid] = 0; wsum[tid] = 0.0f; scur[tid] = 0; }
    __syncthreads();

    for (int k = tid; k < c_n; k += 1024) {
        int2 rc = irec[base + k];
        srw[k] = rc.x;
        unsigned char c = (unsigned char)(rc.y & 255);
        scb[k] = c;
        atomicAdd(&hist[c], 1);
        atomicAdd(&wsum[c], (float)(rc.x & 16383) * (1.0f / 16384.0f));
    }
    __syncthreads();

    // 256-bin scan on the first 256 lanes (barriers reached by all threads)
    int v = 0;
    if (tid < 256) { v = hist[tid]; nbase[tid] = v; }
    __syncthreads();
    for (int d = 1; d < 256; d <<= 1) {
        int u = (tid >= d && tid < 256) ? nbase[tid - d] : 0;
        __syncthreads();
        if (tid < 256) nbase[tid] += u;
        __syncthreads();
    }
    if (tid < 256) {
        int excl = nbase[tid] - v;
        __syncthreads();
        nbase[tid] = excl;
    } else {
        __syncthreads();
    }

    if (tid < 256) {
        int node = b * 256 + tid;
        if (node < N) {
            float dv = rsqrtf(1.0f + wsum[tid]);
            meta[node] = make_int4(base + nbase[tid], v, __float_as_int(dv), 0);
            float xv[F_IN];
            #pragma unroll
            for (int j = 0; j < F_IN; ++j) xv[j] = dv * x[(size_t)node * F_IN + j];
            size_t o = (size_t)node * 6;
            xdh[o + 0] = pack_h2(xv[0], xv[1]);
            xdh[o + 1] = pack_h2(xv[2], xv[3]);
            xdh[o + 2] = pack_h2(xv[4], xv[5]);
            xdh[o + 3] = pack_h2(xv[6], xv[7]);
            xdh[o + 4] = pack_h2(xv[8], 0.0f);
            xdh[o + 5] = 0u;
        }
    }
    __syncthreads();

    for (int k = tid; k < c_n; k += 1024) {
        int rw = srw[k];
        unsigned char c = scb[k];
        int r = atomicAdd(&scur[c], 1);
        csr4[base + nbase[c] + r] = rw;      // (row<<14)|wq, grouped by node
    }
}

// -------- 5: gather layer 1 + fused MLP (4 lanes/node, fp16 tables) --------
__global__ __launch_bounds__(256) void k_g1mlp(
    const int* __restrict__ csr4, const int4* __restrict__ meta,
    const unsigned* __restrict__ xdh,
    const float* __restrict__ W1, const float* __restrict__ b1,
    const float* __restrict__ W2, unsigned* __restrict__ h2dh, int N)
{
    __shared__ float sW1[F_IN * F_HID];
    __shared__ float sb1[F_HID];
    __shared__ float sW2[F_HID * F_OUT];
    for (int t = threadIdx.x; t < F_IN * F_HID; t += 256) sW1[t] = W1[t];
    for (int t = threadIdx.x; t < F_HID;        t += 256) sb1[t] = b1[t];
    for (int t = threadIdx.x; t < F_HID * F_OUT; t += 256) sW2[t] = W2[t];
    __syncthreads();

    int t   = blockIdx.x * 256 + threadIdx.x;
    int i   = t >> 2;
    int sub = t & 3;
    if (i >= N) return;
    int4 m = meta[i];
    float dv = __int_as_float(m.z);

    float acc[F_IN];
    #pragma unroll
    for (int j = 0; j < F_IN; ++j) acc[j] = 0.0f;
    if (sub == 0) {
        size_t o = (size_t)i * 6;
        uint2 u01 = *reinterpret_cast<const uint2*>(xdh + o);
        uint2 u23 = *reinterpret_cast<const uint2*>(xdh + o + 2);
        unsigned u4 = xdh[o + 4];
        float2 f0 = unpack_h2(u01.x), f1 = unpack_h2(u01.y),
               f2 = unpack_h2(u23.x), f3 = unpack_h2(u23.y),
               f4 = unpack_h2(u4);
        acc[0] = f0.x; acc[1] = f0.y; acc[2] = f1.x; acc[3] = f1.y;
        acc[4] = f2.x; acc[5] = f2.y; acc[6] = f3.x; acc[7] = f3.y;
        acc[8] = f4.x;
    }
    int s = m.x, tend = m.x + m.y;
    for (int e = s + sub; e < tend; e += 4) {
        int v = nt_load_int(&csr4[e]);
        int r = (int)((unsigned)v >> 14);
        float wv = (float)(v & 16383) * (1.0f / 16384.0f);
        size_t o = (size_t)r * 6;
        uint2 u01 = *reinterpret_cast<const uint2*>(xdh + o);
        uint2 u23 = *reinterpret_cast<const uint2*>(xdh + o + 2);
        unsigned u4 = xdh[o + 4];
        float2 f0 = unpack_h2(u01.x), f1 = unpack_h2(u01.y),
               f2 = unpack_h2(u23.x), f3 = unpack_h2(u23.y),
               f4 = unpack_h2(u4);
        acc[0] = fmaf(wv, f0.x, acc[0]); acc[1] = fmaf(wv, f0.y, acc[1]);
        acc[2] = fmaf(wv, f1.x, acc[2]); acc[3] = fmaf(wv, f1.y, acc[3]);
        acc[4] = fmaf(wv, f2.x, acc[4]); acc[5] = fmaf(wv, f2.y, acc[5]);
        acc[6] = fmaf(wv, f3.x, acc[6]); acc[7] = fmaf(wv, f3.y, acc[7]);
        acc[8] = fmaf(wv, f4.x, acc[8]);
    }
    #pragma unroll
    for (int d = 1; d < 4; d <<= 1) {
        #pragma unroll
        for (int j = 0; j < F_IN; ++j)
            acc[j] += __shfl_xor(acc[j], d, 4);
    }
    #pragma unroll
    for (int j = 0; j < F_IN; ++j) acc[j] *= dv;

    float o7[F_OUT];
    #pragma unroll
    for (int c = 0; c < F_OUT; ++c) o7[c] = 0.0f;
    int ks = sub * 8;
    #pragma unroll
    for (int k = 0; k < 8; ++k) {
        float hk = sb1[ks + k];
        #pragma unroll
        for (int j = 0; j < F_IN; ++j) hk = fmaf(acc[j], sW1[j * F_HID + ks + k], hk);
        hk = fmaxf(hk, 0.0f);
        #pragma unroll
        for (int c = 0; c < F_OUT; ++c) o7[c] = fmaf(hk, sW2[(ks + k) * F_OUT + c], o7[c]);
    }
    #pragma unroll
    for (int d = 1; d < 4; d <<= 1) {
        #pragma unroll
        for (int c = 0; c < F_OUT; ++c)
            o7[c] += __shfl_xor(o7[c], d, 4);
    }
    float pa = dv * o7[2 * sub];
    float pb = (2 * sub + 1 < F_OUT) ? dv * o7[2 * sub + 1] : 0.0f;
    h2dh[(size_t)i * 4 + sub] = pack_h2(pa, pb);
}

// -------- 6: gather layer 2 + bias + log_softmax (4 lanes/node) --------
__global__ __launch_bounds__(256) void k_g2ls(
    const int* __restrict__ csr4, const int4* __restrict__ meta,
    const unsigned* __restrict__ h2dh, const float* __restrict__ b2,
    float* __restrict__ out, int N)
{
    int t   = blockIdx.x * 256 + threadIdx.x;
    int i   = t >> 2;
    int sub = t & 3;
    if (i >= N) return;
    int4 m = meta[i];
    float dv = __int_as_float(m.z);

    float acc[F_OUT];
    #pragma unroll
    for (int c = 0; c < F_OUT; ++c) acc[c] = 0.0f;
    if (sub == 0) {
        uint4 h4 = *reinterpret_cast<const uint4*>(h2dh + (size_t)i * 4);
        float2 f0 = unpack_h2(h4.x), f1 = unpack_h2(h4.y),
               f2 = unpack_h2(h4.z), f3 = unpack_h2(h4.w);
        acc[0] = f0.x; acc[1] = f0.y; acc[2] = f1.x; acc[3] = f1.y;
        acc[4] = f2.x; acc[5] = f2.y; acc[6] = f3.x;
    }
    int s = m.x, tend = m.x + m.y;
    for (int e = s + sub; e < tend; e += 4) {
        int v = nt_load_int(&csr4[e]);
        int r = (int)((unsigned)v >> 14);
        float wv = (float)(v & 16383) * (1.0f / 16384.0f);
        uint4 h4 = *reinterpret_cast<const uint4*>(h2dh + (size_t)r * 4);
        float2 f0 = unpack_h2(h4.x), f1 = unpack_h2(h4.y),
               f2 = unpack_h2(h4.z), f3 = unpack_h2(h4.w);
        acc[0] = fmaf(wv, f0.x, acc[0]); acc[1] = fmaf(wv, f0.y, acc[1]);
        acc[2] = fmaf(wv, f1.x, acc[2]); acc[3] = fmaf(wv, f1.y, acc[3]);
        acc[4] = fmaf(wv, f2.x, acc[4]); acc[5] = fmaf(wv, f2.y, acc[5]);
        acc[6] = fmaf(wv, f3.x, acc[6]);
    }
    #pragma unroll
    for (int d = 1; d < 4; d <<= 1) {
        #pragma unroll
        for (int c = 0; c < F_OUT; ++c)
            acc[c] += __shfl_xor(acc[c], d, 4);
    }

    float vv[F_OUT];
    float mx = -1e30f;
    #pragma unroll
    for (int c = 0; c < F_OUT; ++c) {
        vv[c] = dv * acc[c] + b2[c];
        mx = fmaxf(mx, vv[c]);
    }
    float ss = 0.0f;
    #pragma unroll
    for (int c = 0; c < F_OUT; ++c) ss += __expf(vv[c] - mx);
    float ls = __logf(ss);
    for (int c = sub; c < F_OUT; c += 4)
        out[(size_t)i * F_OUT + c] = vv[c] - mx - ls;
}

extern "C" void kernel_launch(void* const* d_in, const int* in_sizes, int n_in,
                              void* d_out, int out_size, void* d_ws, size_t ws_size,
                              hipStream_t stream) {
    const float* x  = (const float*)d_in[0];
    const int*   ei = (const int*)  d_in[1];   // [2, E]: row ptr then col ptr
    const float* ew = (const float*)d_in[2];
    const float* W1 = (const float*)d_in[3];
    const float* b1 = (const float*)d_in[4];
    const float* W2 = (const float*)d_in[5];
    const float* b2 = (const float*)d_in[6];
    float* out = (float*)d_out;

    const int N = in_sizes[0] / F_IN;
    const int E = in_sizes[2];
    const int* row = ei;
    const int* col = ei + E;
    const int nchunk = (E + CHUNK - 1) / CHUNK;

    // workspace (~44 MB, no overlays, no aliasing):
    char* p = (char*)d_ws;
    int2*     irec  = (int2*)p;      p += sizeof(int2) * (size_t)NBKT * BCAP;   // 22.8MB
    int*      csr4  = (int*)p;       p += sizeof(int)  * (size_t)NBKT * BCAP;   // 11.4MB
    int4*     meta  = (int4*)p;      p += sizeof(int4) * (size_t)N;             // 2.4MB
    unsigned* xdh   = (unsigned*)p;  p += sizeof(unsigned) * (size_t)N * 6;     // 3.6MB
    unsigned* h2dh  = (unsigned*)p;  p += sizeof(unsigned) * (size_t)N * 4;     // 2.4MB
    int*      ghist = (int*)p;       p += sizeof(int) * (size_t)nchunk * NBKT;  // 1.4MB
    int*      cnt   = (int*)p;       p += sizeof(int) * NBKT;

    const int gN4 = (4 * N + 255) / 256;

    k_hist      <<<nchunk, 1024, 0, stream>>>(col, ghist, E);
    k_scan      <<<NBKT, 256, 0, stream>>>(ghist, cnt, nchunk);
    k_scat      <<<nchunk, 1024, 0, stream>>>(row, col, ew, ghist, irec, E);
    k_sortbucket<<<NBKT, 1024, 0, stream>>>(irec, csr4, cnt, x, meta, xdh, N);
    k_g1mlp     <<<gN4, 256, 0, stream>>>(csr4, meta, xdh, W1, b1, W2, h2dh, N);
    k_g2ls      <<<gN4, 256, 0, stream>>>(csr4, meta, h2dh, b2, out, N);
}

// Round 16
// 131.099 us; speedup vs baseline: 12.0365x; 1.0209x over previous
//
#include <hip/hip_runtime.h>
#include <hip/hip_fp16.h>

constexpr int F_IN  = 9;
constexpr int F_HID = 32;
constexpr int F_OUT = 7;

constexpr int NBKT   = 586;      // ceil(150000/256) buckets of 256 nodes
constexpr int BCAP   = 4864;     // mean 4096 + 12 sigma
constexpr int CHUNK  = 4096;     // edges per hist/scat block
constexpr int EPT    = CHUNK / 1024;   // 4 edges per thread in k_scat

__device__ __forceinline__ int nt_load_int(const int* p) {
    return __builtin_nontemporal_load(p);
}
__device__ __forceinline__ unsigned pack_h2(float a, float b) {
    return (unsigned)__half_as_ushort(__float2half(a)) |
           ((unsigned)__half_as_ushort(__float2half(b)) << 16);
}
__device__ __forceinline__ float2 unpack_h2(unsigned u) {
    return make_float2(__half2float(__ushort_as_half((unsigned short)(u & 0xffffu))),
                       __half2float(__ushort_as_half((unsigned short)(u >> 16))));
}

// ---------- 1: per-chunk histogram over the 586 final buckets ----------
__global__ __launch_bounds__(1024) void k_hist(
    const int* __restrict__ col, int* __restrict__ ghist, int E)
{
    __shared__ int h[NBKT];
    const int tid = threadIdx.x;
    for (int i = tid; i < NBKT; i += 1024) h[i] = 0;
    __syncthreads();
    const int t0 = blockIdx.x * CHUNK;
    const int kend = min(CHUNK, E - t0);
    for (int k = tid; k < kend; k += 1024)
        atomicAdd(&h[col[t0 + k] >> 8], 1);
    __syncthreads();
    int* g = ghist + (size_t)blockIdx.x * NBKT;
    for (int i = tid; i < NBKT; i += 1024) g[i] = h[i];   // coalesced row
}

// ---------- 2: per-bucket exclusive scan down the chunk axis ----------
__global__ __launch_bounds__(256) void k_scan(
    int* __restrict__ ghist, int* __restrict__ cnt, int nchunk)
{
    __shared__ int sc[256];
    const int b = blockIdx.x, tid = threadIdx.x;
    const int per = (nchunk + 255) / 256;
    const int i0 = tid * per, i1 = min(i0 + per, nchunk);

    int sum = 0;
    for (int i = i0; i < i1; ++i) sum += ghist[(size_t)i * NBKT + b];
    sc[tid] = sum; __syncthreads();
    for (int d = 1; d < 256; d <<= 1) {
        int u = (tid >= d) ? sc[tid - d] : 0;
        __syncthreads();
        sc[tid] += u; __syncthreads();
    }
    int run = sc[tid] - sum;                 // exclusive base for this thread
    for (int i = i0; i < i1; ++i) {
        int v = ghist[(size_t)i * NBKT + b];
        ghist[(size_t)i * NBKT + b] = run;
        run += v;
    }
    if (tid == 255) cnt[b] = run;            // total edges in bucket b
}

// ---------- 3: LDS-bucket-sorted scatter (coalesced run writes) ----------
__global__ __launch_bounds__(1024) void k_scat(
    const int* __restrict__ row, const int* __restrict__ col,
    const float* __restrict__ w, const int* __restrict__ ghist,
    int* __restrict__ irA, unsigned char* __restrict__ irB, int E)
{
    __shared__ int           sRW[CHUNK];     // 16 KB  sorted records
    __shared__ int           sDst[CHUNK];    // 16 KB  global destinations
    __shared__ unsigned char sCL[CHUNK];     // 4 KB   sorted col-low bytes
    __shared__ int hist[NBKT];               // hist -> lbase
    __shared__ int lcur[NBKT];
    __shared__ int sbase[NBKT];
    __shared__ int sc[1024];

    const int tid = threadIdx.x;
    const int* g = ghist + (size_t)blockIdx.x * NBKT;
    for (int i = tid; i < NBKT; i += 1024) { sbase[i] = g[i]; hist[i] = 0; lcur[i] = 0; }
    __syncthreads();

    const int t0 = blockIdx.x * CHUNK;
    const int kend = min(CHUNK, E - t0);

    int rRW[EPT], rBC[EPT], nr = 0;
    for (int k = tid; k < kend; k += 1024) {
        int e = t0 + k;
        int c = col[e];
        int wq = min((int)(w[e] * 16384.0f + 0.5f), 16383);
        rRW[nr] = (row[e] << 14) | wq;
        rBC[nr] = c;
        atomicAdd(&hist[c >> 8], 1);
        ++nr;
    }
    __syncthreads();

    // exclusive scan of 586 bins (1024-wide Hillis-Steele)
    int v = (tid < NBKT) ? hist[tid] : 0;
    sc[tid] = v; __syncthreads();
    for (int d = 1; d < 1024; d <<= 1) {
        int u = (tid >= d) ? sc[tid - d] : 0;
        __syncthreads();
        sc[tid] += u; __syncthreads();
    }
    if (tid < NBKT) hist[tid] = sc[tid] - v;       // lbase
    __syncthreads();

    // scatter into bucket-sorted LDS; precompute global destination
    for (int q = 0; q < nr; ++q) {
        int c = rBC[q];
        int b = c >> 8;
        int rank = atomicAdd(&lcur[b], 1);
        int p = hist[b] + rank;
        sRW[p] = rRW[q];
        sCL[p] = (unsigned char)(c & 255);
        int gp = sbase[b] + rank;
        sDst[p] = (gp < BCAP) ? (b * BCAP + gp) : -1;  // guard (never trips)
    }
    __syncthreads();

    // write-out: consecutive threads -> consecutive sorted positions -> runs
    for (int p = tid; p < kend; p += 1024) {
        int d = sDst[p];
        if (d >= 0) { irA[d] = sRW[p]; irB[d] = sCL[p]; }
    }
}

// ---------- 4: in-bucket sort by node; csr4, meta, fp16 xd ------
__global__ __launch_bounds__(1024) void k_sortbucket(
    const int* __restrict__ irA, const unsigned char* __restrict__ irB,
    int* __restrict__ csr4, const int* __restrict__ cnt,
    const float* __restrict__ x, int4* __restrict__ meta,
    unsigned* __restrict__ xdh, int N)
{
    __shared__ int           srw[BCAP];      // 19456 B
    __shared__ unsigned char scb[BCAP];      // 4864 B
    __shared__ int   hist[256];
    __shared__ float wsum[256];
    __shared__ int   nbase[256];
    __shared__ int   scur[256];

    const int b    = blockIdx.x;
    const int tid  = threadIdx.x;
    const int base = b * BCAP;
    const int c_n  = min(cnt[b], BCAP);

    if (tid < 256) { hist[tid] = 0; wsum[tid] = 0.0f; scur[tid] = 0; }
    __syncthreads();

    for (int k = tid; k < c_n; k += 1024) {
        int rw = irA[base + k];
        unsigned char c = irB[base + k];
        srw[k] = rw;
        scb[k] = c;
        atomicAdd(&hist[c], 1);
        atomicAdd(&wsum[c], (float)(rw & 16383) * (1.0f / 16384.0f));
    }
    __syncthreads();

    // 256-bin scan on the first 256 lanes (barriers reached by all threads)
    int v = 0;
    if (tid < 256) { v = hist[tid]; nbase[tid] = v; }
    __syncthreads();
    for (int d = 1; d < 256; d <<= 1) {
        int u = (tid >= d && tid < 256) ? nbase[tid - d] : 0;
        __syncthreads();
        if (tid < 256) nbase[tid] += u;
        __syncthreads();
    }
    if (tid < 256) {
        int excl = nbase[tid] - v;
        __syncthreads();
        nbase[tid] = excl;
    } else {
        __syncthreads();
    }

    if (tid < 256) {
        int node = b * 256 + tid;
        if (node < N) {
            float dv = rsqrtf(1.0f + wsum[tid]);
            meta[node] = make_int4(base + nbase[tid], v, __float_as_int(dv), 0);
            float xv[F_IN];
            #pragma unroll
            for (int j = 0; j < F_IN; ++j) xv[j] = dv * x[(size_t)node * F_IN + j];
            size_t o = (size_t)node * 6;
            xdh[o + 0] = pack_h2(xv[0], xv[1]);
            xdh[o + 1] = pack_h2(xv[2], xv[3]);
            xdh[o + 2] = pack_h2(xv[4], xv[5]);
            xdh[o + 3] = pack_h2(xv[6], xv[7]);
            xdh[o + 4] = pack_h2(xv[8], 0.0f);
            xdh[o + 5] = 0u;
        }
    }
    __syncthreads();

    for (int k = tid; k < c_n; k += 1024) {
        int rw = srw[k];
        unsigned char c = scb[k];
        int r = atomicAdd(&scur[c], 1);
        csr4[base + nbase[c] + r] = rw;      // (row<<14)|wq, grouped by node
    }
}

// -------- 5: gather layer 1 + fused MLP (4 lanes/node, fp16 tables) --------
__global__ __launch_bounds__(256) void k_g1mlp(
    const int* __restrict__ csr4, const int4* __restrict__ meta,
    const unsigned* __restrict__ xdh,
    const float* __restrict__ W1, const float* __restrict__ b1,
    const float* __restrict__ W2, unsigned* __restrict__ h2dh, int N)
{
    __shared__ float sW1[F_IN * F_HID];
    __shared__ float sb1[F_HID];
    __shared__ float sW2[F_HID * F_OUT];
    for (int t = threadIdx.x; t < F_IN * F_HID; t += 256) sW1[t] = W1[t];
    for (int t = threadIdx.x; t < F_HID;        t += 256) sb1[t] = b1[t];
    for (int t = threadIdx.x; t < F_HID * F_OUT; t += 256) sW2[t] = W2[t];
    __syncthreads();

    int t   = blockIdx.x * 256 + threadIdx.x;
    int i   = t >> 2;
    int sub = t & 3;
    if (i >= N) return;
    int4 m = meta[i];
    float dv = __int_as_float(m.z);

    float acc[F_IN];
    #pragma unroll
    for (int j = 0; j < F_IN; ++j) acc[j] = 0.0f;
    if (sub == 0) {
        size_t o = (size_t)i * 6;
        uint2 u01 = *reinterpret_cast<const uint2*>(xdh + o);
        uint2 u23 = *reinterpret_cast<const uint2*>(xdh + o + 2);
        unsigned u4 = xdh[o + 4];
        float2 f0 = unpack_h2(u01.x), f1 = unpack_h2(u01.y),
               f2 = unpack_h2(u23.x), f3 = unpack_h2(u23.y),
               f4 = unpack_h2(u4);
        acc[0] = f0.x; acc[1] = f0.y; acc[2] = f1.x; acc[3] = f1.y;
        acc[4] = f2.x; acc[5] = f2.y; acc[6] = f3.x; acc[7] = f3.y;
        acc[8] = f4.x;
    }
    int s = m.x, tend = m.x + m.y;
    for (int e = s + sub; e < tend; e += 4) {
        int v = nt_load_int(&csr4[e]);
        int r = (int)((unsigned)v >> 14);
        float wv = (float)(v & 16383) * (1.0f / 16384.0f);
        size_t o = (size_t)r * 6;
        uint2 u01 = *reinterpret_cast<const uint2*>(xdh + o);
        uint2 u23 = *reinterpret_cast<const uint2*>(xdh + o + 2);
        unsigned u4 = xdh[o + 4];
        float2 f0 = unpack_h2(u01.x), f1 = unpack_h2(u01.y),
               f2 = unpack_h2(u23.x), f3 = unpack_h2(u23.y),
               f4 = unpack_h2(u4);
        acc[0] = fmaf(wv, f0.x, acc[0]); acc[1] = fmaf(wv, f0.y, acc[1]);
        acc[2] = fmaf(wv, f1.x, acc[2]); acc[3] = fmaf(wv, f1.y, acc[3]);
        acc[4] = fmaf(wv, f2.x, acc[4]); acc[5] = fmaf(wv, f2.y, acc[5]);
        acc[6] = fmaf(wv, f3.x, acc[6]); acc[7] = fmaf(wv, f3.y, acc[7]);
        acc[8] = fmaf(wv, f4.x, acc[8]);
    }
    #pragma unroll
    for (int d = 1; d < 4; d <<= 1) {
        #pragma unroll
        for (int j = 0; j < F_IN; ++j)
            acc[j] += __shfl_xor(acc[j], d, 4);
    }
    #pragma unroll
    for (int j = 0; j < F_IN; ++j) acc[j] *= dv;

    float o7[F_OUT];
    #pragma unroll
    for (int c = 0; c < F_OUT; ++c) o7[c] = 0.0f;
    int ks = sub * 8;
    #pragma unroll
    for (int k = 0; k < 8; ++k) {
        float hk = sb1[ks + k];
        #pragma unroll
        for (int j = 0; j < F_IN; ++j) hk = fmaf(acc[j], sW1[j * F_HID + ks + k], hk);
        hk = fmaxf(hk, 0.0f);
        #pragma unroll
        for (int c = 0; c < F_OUT; ++c) o7[c] = fmaf(hk, sW2[(ks + k) * F_OUT + c], o7[c]);
    }
    #pragma unroll
    for (int d = 1; d < 4; d <<= 1) {
        #pragma unroll
        for (int c = 0; c < F_OUT; ++c)
            o7[c] += __shfl_xor(o7[c], d, 4);
    }
    float pa = dv * o7[2 * sub];
    float pb = (2 * sub + 1 < F_OUT) ? dv * o7[2 * sub + 1] : 0.0f;
    h2dh[(size_t)i * 4 + sub] = pack_h2(pa, pb);
}

// -------- 6: gather layer 2 + bias + log_softmax (4 lanes/node) --------
__global__ __launch_bounds__(256) void k_g2ls(
    const int* __restrict__ csr4, const int4* __restrict__ meta,
    const unsigned* __restrict__ h2dh, const float* __restrict__ b2,
    float* __restrict__ out, int N)
{
    int t   = blockIdx.x * 256 + threadIdx.x;
    int i   = t >> 2;
    int sub = t & 3;
    if (i >= N) return;
    int4 m = meta[i];
    float dv = __int_as_float(m.z);

    float acc[F_OUT];
    #pragma unroll
    for (int c = 0; c < F_OUT; ++c) acc[c] = 0.0f;
    if (sub == 0) {
        uint4 h4 = *reinterpret_cast<const uint4*>(h2dh + (size_t)i * 4);
        float2 f0 = unpack_h2(h4.x), f1 = unpack_h2(h4.y),
               f2 = unpack_h2(h4.z), f3 = unpack_h2(h4.w);
        acc[0] = f0.x; acc[1] = f0.y; acc[2] = f1.x; acc[3] = f1.y;
        acc[4] = f2.x; acc[5] = f2.y; acc[6] = f3.x;
    }
    int s = m.x, tend = m.x + m.y;
    for (int e = s + sub; e < tend; e += 4) {
        int v = nt_load_int(&csr4[e]);
        int r = (int)((unsigned)v >> 14);
        float wv = (float)(v & 16383) * (1.0f / 16384.0f);
        uint4 h4 = *reinterpret_cast<const uint4*>(h2dh + (size_t)r * 4);
        float2 f0 = unpack_h2(h4.x), f1 = unpack_h2(h4.y),
               f2 = unpack_h2(h4.z), f3 = unpack_h2(h4.w);
        acc[0] = fmaf(wv, f0.x, acc[0]); acc[1] = fmaf(wv, f0.y, acc[1]);
        acc[2] = fmaf(wv, f1.x, acc[2]); acc[3] = fmaf(wv, f1.y, acc[3]);
        acc[4] = fmaf(wv, f2.x, acc[4]); acc[5] = fmaf(wv, f2.y, acc[5]);
        acc[6] = fmaf(wv, f3.x, acc[6]);
    }
    #pragma unroll
    for (int d = 1; d < 4; d <<= 1) {
        #pragma unroll
        for (int c = 0; c < F_OUT; ++c)
            acc[c] += __shfl_xor(acc[c], d, 4);
    }

    float vv[F_OUT];
    float mx = -1e30f;
    #pragma unroll
    for (int c = 0; c < F_OUT; ++c) {
        vv[c] = dv * acc[c] + b2[c];
        mx = fmaxf(mx, vv[c]);
    }
    float ss = 0.0f;
    #pragma unroll
    for (int c = 0; c < F_OUT; ++c) ss += __expf(vv[c] - mx);
    float ls = __logf(ss);
    for (int c = sub; c < F_OUT; c += 4)
        out[(size_t)i * F_OUT + c] = vv[c] - mx - ls;
}

extern "C" void kernel_launch(void* const* d_in, const int* in_sizes, int n_in,
                              void* d_out, int out_size, void* d_ws, size_t ws_size,
                              hipStream_t stream) {
    const float* x  = (const float*)d_in[0];
    const int*   ei = (const int*)  d_in[1];   // [2, E]: row ptr then col ptr
    const float* ew = (const float*)d_in[2];
    const float* W1 = (const float*)d_in[3];
    const float* b1 = (const float*)d_in[4];
    const float* W2 = (const float*)d_in[5];
    const float* b2 = (const float*)d_in[6];
    float* out = (float*)d_out;

    const int N = in_sizes[0] / F_IN;
    const int E = in_sizes[2];
    const int* row = ei;
    const int* col = ei + E;
    const int nchunk = (E + CHUNK - 1) / CHUNK;

    // workspace (~35.5 MB, no overlays):
    char* p = (char*)d_ws;
    int4*     meta  = (int4*)p;      p += sizeof(int4) * (size_t)N;             // 2.4MB (16B aligned first)
    int*      irA   = (int*)p;       p += sizeof(int)  * (size_t)NBKT * BCAP;   // 11.4MB
    int*      csr4  = (int*)p;       p += sizeof(int)  * (size_t)NBKT * BCAP;   // 11.4MB
    unsigned* xdh   = (unsigned*)p;  p += sizeof(unsigned) * (size_t)N * 6;     // 3.6MB
    unsigned* h2dh  = (unsigned*)p;  p += sizeof(unsigned) * (size_t)N * 4;     // 2.4MB
    int*      ghist = (int*)p;       p += sizeof(int) * (size_t)nchunk * NBKT;  // 1.4MB
    int*      cnt   = (int*)p;       p += sizeof(int) * NBKT;
    unsigned char* irB = (unsigned char*)p;                                     // 2.85MB

    const int gN4 = (4 * N + 255) / 256;

    k_hist      <<<nchunk, 1024, 0, stream>>>(col, ghist, E);
    k_scan      <<<NBKT, 256, 0, stream>>>(ghist, cnt, nchunk);
    k_scat      <<<nchunk, 1024, 0, stream>>>(row, col, ew, ghist, irA, irB, E);
    k_sortbucket<<<NBKT, 1024, 0, stream>>>(irA, irB, csr4, cnt, x, meta, xdh, N);
    k_g1mlp     <<<gN4, 256, 0, stream>>>(csr4, meta, xdh, W1, b1, W2, h2dh, N);
    k_g2ls      <<<gN4, 256, 0, stream>>>(csr4, meta, h2dh, b2, out, N);
}